// Round 1
// baseline (2301.095 us; speedup 1.0000x reference)
//
#include <hip/hip_runtime.h>

// GCN 2-layer GraphConv (norm='both'), fp32, push-mode atomic scatter version.
// ws layout (floats): [out_norm N | in_norm N | agg1 64N | h1 64N | h2 32N] = 162N floats (~64.8 MB)

__global__ __launch_bounds__(256) void gcn_deg(const int* __restrict__ src,
                                               const int* __restrict__ dst,
                                               float* __restrict__ degs,
                                               float* __restrict__ degd, int E) {
  int e = blockIdx.x * 256 + threadIdx.x;
  if (e < E) {
    atomicAdd(&degs[src[e]], 1.0f);
    atomicAdd(&degd[dst[e]], 1.0f);
  }
}

__global__ __launch_bounds__(256) void gcn_norm(float* __restrict__ buf, int n2) {
  int i = blockIdx.x * 256 + threadIdx.x;
  if (i < n2) buf[i] = rsqrtf(fmaxf(buf[i], 1.0f));
}

// h1[N,64] = (x * out_norm[:,None]) @ W1[64,64]
// 16 rows/block, 256 threads: lane c = t&63 (col), rq = t>>6; each thread 4 rows.
__global__ __launch_bounds__(256) void gcn_xw1(const float* __restrict__ x,
                                               const float* __restrict__ W,
                                               const float* __restrict__ out_norm,
                                               float* __restrict__ h1, int n) {
  __shared__ float Ws[64 * 64];
  __shared__ float xs[16 * 64];
  int t = threadIdx.x;
#pragma unroll
  for (int i = 0; i < 16; i++) Ws[i * 256 + t] = W[i * 256 + t];
  int row0 = blockIdx.x * 16;
#pragma unroll
  for (int i = 0; i < 4; i++) {
    int idx = i * 256 + t;       // 0..1023
    int r = idx >> 6, k = idx & 63;
    int row = row0 + r;
    xs[idx] = (row < n) ? x[row * 64 + k] * out_norm[row] : 0.0f;
  }
  __syncthreads();
  int c = t & 63, rq = t >> 6;   // rq in 0..3
  float acc[4] = {0.f, 0.f, 0.f, 0.f};
#pragma unroll 16
  for (int k = 0; k < 64; k++) {
    float w = Ws[k * 64 + c];    // lanes c=0..63 -> 2 lanes/bank, free
#pragma unroll
    for (int rr = 0; rr < 4; rr++) acc[rr] += xs[(rq + rr * 4) * 64 + k] * w;  // broadcast
  }
#pragma unroll
  for (int rr = 0; rr < 4; rr++) {
    int row = row0 + rq + rr * 4;
    if (row < n) h1[row * 64 + c] = acc[rr];
  }
}

// push scatter, 64 feats: 16 lanes/edge, float4 gather + 4 atomics each
__global__ __launch_bounds__(256) void gcn_scatter64(const int* __restrict__ src,
                                                     const int* __restrict__ dst,
                                                     const float* __restrict__ h,
                                                     float* __restrict__ agg, int E) {
  int gid = blockIdx.x * 256 + threadIdx.x;
  int e = gid >> 4, l = gid & 15;
  if (e >= E) return;
  int s = src[e], d = dst[e];
  float4 v = ((const float4*)h)[(size_t)s * 16 + l];
  float* p = agg + (size_t)d * 64 + l * 4;
  atomicAdd(p + 0, v.x);
  atomicAdd(p + 1, v.y);
  atomicAdd(p + 2, v.z);
  atomicAdd(p + 3, v.w);
}

// h2[N,32] = (relu(agg1 * in_norm + b1) * out_norm) @ W2[64,32]
__global__ __launch_bounds__(256) void gcn_xw2(const float* __restrict__ agg1,
                                               const float* __restrict__ W,
                                               const float* __restrict__ b1,
                                               const float* __restrict__ in_norm,
                                               const float* __restrict__ out_norm,
                                               float* __restrict__ h2, int n) {
  __shared__ float Ws[64 * 32];
  __shared__ float xs[16 * 64];
  int t = threadIdx.x;
#pragma unroll
  for (int i = 0; i < 8; i++) Ws[i * 256 + t] = W[i * 256 + t];
  int row0 = blockIdx.x * 16;
#pragma unroll
  for (int i = 0; i < 4; i++) {
    int idx = i * 256 + t;
    int r = idx >> 6, k = idx & 63;
    int row = row0 + r;
    float v = 0.0f;
    if (row < n)
      v = fmaxf(agg1[(size_t)row * 64 + k] * in_norm[row] + b1[k], 0.0f) * out_norm[row];
    xs[idx] = v;
  }
  __syncthreads();
  int c = t & 31, rq = t >> 5;   // rq in 0..7; rows rq and rq+8
  float acc0 = 0.f, acc1 = 0.f;
#pragma unroll 16
  for (int k = 0; k < 64; k++) {
    float w = Ws[k * 32 + c];    // 32 addrs over 32 banks, 2-lane broadcast, free
    acc0 += xs[rq * 64 + k] * w;
    acc1 += xs[(rq + 8) * 64 + k] * w;
  }
  int row = row0 + rq;
  if (row < n) h2[(size_t)row * 32 + c] = acc0;
  row = row0 + rq + 8;
  if (row < n) h2[(size_t)row * 32 + c] = acc1;
}

// push scatter, 32 feats: 8 lanes/edge
__global__ __launch_bounds__(256) void gcn_scatter32(const int* __restrict__ src,
                                                     const int* __restrict__ dst,
                                                     const float* __restrict__ h,
                                                     float* __restrict__ agg, int E) {
  int gid = blockIdx.x * 256 + threadIdx.x;
  int e = gid >> 3, l = gid & 7;
  if (e >= E) return;
  int s = src[e], d = dst[e];
  float4 v = ((const float4*)h)[(size_t)s * 8 + l];
  float* p = agg + (size_t)d * 32 + l * 4;
  atomicAdd(p + 0, v.x);
  atomicAdd(p + 1, v.y);
  atomicAdd(p + 2, v.z);
  atomicAdd(p + 3, v.w);
}

// out = out * in_norm[:,None] + b2  (in place, float4)
__global__ __launch_bounds__(256) void gcn_finish(float* __restrict__ out,
                                                  const float* __restrict__ in_norm,
                                                  const float* __restrict__ b2, int n8) {
  int gid = blockIdx.x * 256 + threadIdx.x;
  if (gid < n8) {
    int node = gid >> 3, c4 = gid & 7;
    float4 v = ((float4*)out)[gid];
    float4 bb = ((const float4*)b2)[c4];
    float s = in_norm[node];
    v.x = v.x * s + bb.x;
    v.y = v.y * s + bb.y;
    v.z = v.z * s + bb.z;
    v.w = v.w * s + bb.w;
    ((float4*)out)[gid] = v;
  }
}

extern "C" void kernel_launch(void* const* d_in, const int* in_sizes, int n_in,
                              void* d_out, int out_size, void* d_ws, size_t ws_size,
                              hipStream_t stream) {
  const float* x  = (const float*)d_in[0];
  const int*   src = (const int*)d_in[1];
  const int*   dst = (const int*)d_in[2];
  const float* W1 = (const float*)d_in[3];
  const float* b1 = (const float*)d_in[4];
  const float* W2 = (const float*)d_in[5];
  const float* b2 = (const float*)d_in[6];
  float* out = (float*)d_out;

  const int N = in_sizes[0] / 64;   // 100000
  const int E = in_sizes[1];        // 1600000

  float* wsf = (float*)d_ws;
  float* out_norm = wsf;                       // N
  float* in_norm  = wsf + N;                   // N
  float* agg1     = wsf + 2 * (size_t)N;       // 64N
  float* h1       = wsf + 66 * (size_t)N;      // 64N
  float* h2       = wsf + 130 * (size_t)N;     // 32N

  // zero: degree/norm buffers + agg1 (contiguous), and d_out (agg2 target)
  hipMemsetAsync(wsf, 0, (size_t)66 * N * sizeof(float), stream);
  hipMemsetAsync(out, 0, (size_t)out_size * sizeof(float), stream);

  gcn_deg<<<(E + 255) / 256, 256, 0, stream>>>(src, dst, out_norm, in_norm, E);
  gcn_norm<<<(2 * N + 255) / 256, 256, 0, stream>>>(out_norm, 2 * N);
  gcn_xw1<<<(N + 15) / 16, 256, 0, stream>>>(x, W1, out_norm, h1, N);
  gcn_scatter64<<<(E * 16 + 255) / 256, 256, 0, stream>>>(src, dst, h1, agg1, E);
  gcn_xw2<<<(N + 15) / 16, 256, 0, stream>>>(agg1, W2, b1, in_norm, out_norm, h2, N);
  gcn_scatter32<<<(E * 8 + 255) / 256, 256, 0, stream>>>(src, dst, h2, out, E);
  gcn_finish<<<(N * 8 + 255) / 256, 256, 0, stream>>>(out, in_norm, b2, N * 8);
}

// Round 2
// 453.216 us; speedup vs baseline: 5.0773x; 5.0773x over previous
//
#include <hip/hip_runtime.h>

// GCN 2-layer GraphConv (norm='both'), fp32.
// Round 2: CSR-build + pull-mode aggregation (zero float atomics).
//
// ws layout:
//   int   hist_s[N], hist_d[N], cursor[N], rowptr[N], bsum[1024], col[E]
//   float out_norm[N], in_norm[N], h1[64N] (reused as h2[32N]), agg1[64N]

#define SCAN_BLK 1024  // elements per scan block (256 thr x 4)

__global__ __launch_bounds__(256) void gcn_hist(const int* __restrict__ src,
                                                const int* __restrict__ dst,
                                                int* __restrict__ hist_s,
                                                int* __restrict__ hist_d, int E) {
  int e = blockIdx.x * 256 + threadIdx.x;
  if (e < E) {
    atomicAdd(&hist_s[src[e]], 1);
    atomicAdd(&hist_d[dst[e]], 1);
  }
}

__global__ __launch_bounds__(256) void gcn_norm(const int* __restrict__ hist_s,
                                                const int* __restrict__ hist_d,
                                                float* __restrict__ out_norm,
                                                float* __restrict__ in_norm, int n) {
  int i = blockIdx.x * 256 + threadIdx.x;
  if (i < n) {
    out_norm[i] = rsqrtf(fmaxf((float)hist_s[i], 1.0f));
    in_norm[i]  = rsqrtf(fmaxf((float)hist_d[i], 1.0f));
  }
}

// ---- 3-kernel exclusive scan of hist_d -> rowptr ----
__global__ __launch_bounds__(256) void scan_local(const int* __restrict__ in,
                                                  int* __restrict__ out,
                                                  int* __restrict__ bsum, int n) {
  __shared__ int tmp[256];
  int t = threadIdx.x;
  int base = blockIdx.x * SCAN_BLK + t * 4;
  int v[4], s = 0;
#pragma unroll
  for (int i = 0; i < 4; i++) {
    v[i] = (base + i < n) ? in[base + i] : 0;
    s += v[i];
  }
  tmp[t] = s;
  __syncthreads();
  // Hillis-Steele inclusive scan over 256
#pragma unroll
  for (int off = 1; off < 256; off <<= 1) {
    int val = (t >= off) ? tmp[t - off] : 0;
    __syncthreads();
    tmp[t] += val;
    __syncthreads();
  }
  int excl = tmp[t] - s;  // exclusive prefix for this thread
  int run = excl;
#pragma unroll
  for (int i = 0; i < 4; i++) {
    if (base + i < n) out[base + i] = run;
    run += v[i];
  }
  if (t == 255) bsum[blockIdx.x] = tmp[255];
}

__global__ __launch_bounds__(128) void scan_bsums(int* __restrict__ bsum, int nb) {
  __shared__ int tmp[128];
  int t = threadIdx.x;
  int v = (t < nb) ? bsum[t] : 0;
  tmp[t] = v;
  __syncthreads();
#pragma unroll
  for (int off = 1; off < 128; off <<= 1) {
    int val = (t >= off) ? tmp[t - off] : 0;
    __syncthreads();
    tmp[t] += val;
    __syncthreads();
  }
  if (t < nb) bsum[t] = tmp[t] - v;  // exclusive
}

__global__ __launch_bounds__(256) void scan_add(int* __restrict__ out,
                                                const int* __restrict__ bsum, int n) {
  int i = blockIdx.x * 256 + threadIdx.x;
  if (i < n) out[i] += bsum[i / SCAN_BLK];
}

// ---- CSR placement: col[rowptr[dst]+pos] = src ----
__global__ __launch_bounds__(256) void gcn_place(const int* __restrict__ src,
                                                 const int* __restrict__ dst,
                                                 const int* __restrict__ rowptr,
                                                 int* __restrict__ cursor,
                                                 int* __restrict__ col, int E) {
  int e = blockIdx.x * 256 + threadIdx.x;
  if (e < E) {
    int d = dst[e];
    int pos = atomicAdd(&cursor[d], 1);
    col[rowptr[d] + pos] = src[e];
  }
}

// ---- h1[N,64] = (x * out_norm[:,None]) @ W1[64,64] ----
__global__ __launch_bounds__(256) void gcn_xw1(const float* __restrict__ x,
                                               const float* __restrict__ W,
                                               const float* __restrict__ out_norm,
                                               float* __restrict__ h1, int n) {
  __shared__ float Ws[64 * 64];
  __shared__ float xs[16 * 64];
  int t = threadIdx.x;
#pragma unroll
  for (int i = 0; i < 16; i++) Ws[i * 256 + t] = W[i * 256 + t];
  int row0 = blockIdx.x * 16;
#pragma unroll
  for (int i = 0; i < 4; i++) {
    int idx = i * 256 + t;
    int r = idx >> 6, k = idx & 63;
    int row = row0 + r;
    xs[idx] = (row < n) ? x[row * 64 + k] * out_norm[row] : 0.0f;
  }
  __syncthreads();
  int c = t & 63, rq = t >> 6;
  float acc[4] = {0.f, 0.f, 0.f, 0.f};
#pragma unroll 16
  for (int k = 0; k < 64; k++) {
    float w = Ws[k * 64 + c];
#pragma unroll
    for (int rr = 0; rr < 4; rr++) acc[rr] += xs[(rq + rr * 4) * 64 + k] * w;
  }
#pragma unroll
  for (int rr = 0; rr < 4; rr++) {
    int row = row0 + rq + rr * 4;
    if (row < n) h1[row * 64 + c] = acc[rr];
  }
}

// ---- pull aggregation, 64 feats: 1 wave per node, lane = feature ----
__global__ __launch_bounds__(256) void gcn_pull64(const int* __restrict__ rowptr,
                                                  const int* __restrict__ deg,
                                                  const int* __restrict__ col,
                                                  const float* __restrict__ h,
                                                  float* __restrict__ agg, int n) {
  int t = threadIdx.x;
  int node = blockIdx.x * 4 + (t >> 6);
  if (node >= n) return;
  int lane = t & 63;
  int j = rowptr[node];
  int end = j + deg[node];
  float a0 = 0.f, a1 = 0.f, a2 = 0.f, a3 = 0.f;
  for (; j + 4 <= end; j += 4) {
    int s0 = col[j], s1 = col[j + 1], s2 = col[j + 2], s3 = col[j + 3];
    a0 += h[(size_t)s0 * 64 + lane];
    a1 += h[(size_t)s1 * 64 + lane];
    a2 += h[(size_t)s2 * 64 + lane];
    a3 += h[(size_t)s3 * 64 + lane];
  }
  for (; j < end; j++) a0 += h[(size_t)col[j] * 64 + lane];
  agg[(size_t)node * 64 + lane] = (a0 + a1) + (a2 + a3);
}

// ---- h2[N,32] = (relu(agg1 * in_norm + b1) * out_norm) @ W2[64,32] ----
__global__ __launch_bounds__(256) void gcn_xw2(const float* __restrict__ agg1,
                                               const float* __restrict__ W,
                                               const float* __restrict__ b1,
                                               const float* __restrict__ in_norm,
                                               const float* __restrict__ out_norm,
                                               float* __restrict__ h2, int n) {
  __shared__ float Ws[64 * 32];
  __shared__ float xs[16 * 64];
  int t = threadIdx.x;
#pragma unroll
  for (int i = 0; i < 8; i++) Ws[i * 256 + t] = W[i * 256 + t];
  int row0 = blockIdx.x * 16;
#pragma unroll
  for (int i = 0; i < 4; i++) {
    int idx = i * 256 + t;
    int r = idx >> 6, k = idx & 63;
    int row = row0 + r;
    float v = 0.0f;
    if (row < n)
      v = fmaxf(agg1[(size_t)row * 64 + k] * in_norm[row] + b1[k], 0.0f) * out_norm[row];
    xs[idx] = v;
  }
  __syncthreads();
  int c = t & 31, rq = t >> 5;
  float acc0 = 0.f, acc1 = 0.f;
#pragma unroll 16
  for (int k = 0; k < 64; k++) {
    float w = Ws[k * 32 + c];
    acc0 += xs[rq * 64 + k] * w;
    acc1 += xs[(rq + 8) * 64 + k] * w;
  }
  int row = row0 + rq;
  if (row < n) h2[(size_t)row * 32 + c] = acc0;
  row = row0 + rq + 8;
  if (row < n) h2[(size_t)row * 32 + c] = acc1;
}

// ---- pull 32 feats + fused epilogue: out = agg * in_norm + b2 ----
__global__ __launch_bounds__(256) void gcn_pull32(const int* __restrict__ rowptr,
                                                  const int* __restrict__ deg,
                                                  const int* __restrict__ col,
                                                  const float* __restrict__ h,
                                                  const float* __restrict__ in_norm,
                                                  const float* __restrict__ b2,
                                                  float* __restrict__ out, int n) {
  int t = threadIdx.x;
  int node = blockIdx.x * 8 + (t >> 5);
  if (node >= n) return;
  int lane = t & 31;
  int j = rowptr[node];
  int end = j + deg[node];
  float a0 = 0.f, a1 = 0.f, a2 = 0.f, a3 = 0.f;
  for (; j + 4 <= end; j += 4) {
    int s0 = col[j], s1 = col[j + 1], s2 = col[j + 2], s3 = col[j + 3];
    a0 += h[(size_t)s0 * 32 + lane];
    a1 += h[(size_t)s1 * 32 + lane];
    a2 += h[(size_t)s2 * 32 + lane];
    a3 += h[(size_t)s3 * 32 + lane];
  }
  for (; j < end; j++) a0 += h[(size_t)col[j] * 32 + lane];
  float acc = (a0 + a1) + (a2 + a3);
  out[(size_t)node * 32 + lane] = acc * in_norm[node] + b2[lane];
}

extern "C" void kernel_launch(void* const* d_in, const int* in_sizes, int n_in,
                              void* d_out, int out_size, void* d_ws, size_t ws_size,
                              hipStream_t stream) {
  const float* x   = (const float*)d_in[0];
  const int*   src = (const int*)d_in[1];
  const int*   dst = (const int*)d_in[2];
  const float* W1  = (const float*)d_in[3];
  const float* b1  = (const float*)d_in[4];
  const float* W2  = (const float*)d_in[5];
  const float* b2  = (const float*)d_in[6];
  float* out = (float*)d_out;

  const int N = in_sizes[0] / 64;   // 100000
  const int E = in_sizes[1];        // 1600000
  const int NB = (N + SCAN_BLK - 1) / SCAN_BLK;  // 98

  int* hist_s = (int*)d_ws;            // N
  int* hist_d = hist_s + N;            // N
  int* cursor = hist_d + N;            // N
  int* rowptr = cursor + N;            // N
  int* bsum   = rowptr + N;            // 1024 pad
  int* col    = bsum + 1024;           // E
  float* out_norm = (float*)(col + E); // N
  float* in_norm  = out_norm + N;      // N
  float* h1       = in_norm + N;       // 64N (reused as h2: 32N)
  float* agg1     = h1 + (size_t)64 * N; // 64N
  float* h2       = h1;                // alias: h1 dead after pull64->agg1->xw2

  // zero the three atomic counter arrays only
  hipMemsetAsync(hist_s, 0, (size_t)3 * N * sizeof(int), stream);

  gcn_hist<<<(E + 255) / 256, 256, 0, stream>>>(src, dst, hist_s, hist_d, E);
  gcn_norm<<<(N + 255) / 256, 256, 0, stream>>>(hist_s, hist_d, out_norm, in_norm, N);
  scan_local<<<NB, 256, 0, stream>>>(hist_d, rowptr, bsum, N);
  scan_bsums<<<1, 128, 0, stream>>>(bsum, NB);
  scan_add<<<(N + 255) / 256, 256, 0, stream>>>(rowptr, bsum, N);
  gcn_place<<<(E + 255) / 256, 256, 0, stream>>>(src, dst, rowptr, cursor, col, E);
  gcn_xw1<<<(N + 15) / 16, 256, 0, stream>>>(x, W1, out_norm, h1, N);
  gcn_pull64<<<(N + 3) / 4, 256, 0, stream>>>(rowptr, hist_d, col, h1, agg1, N);
  gcn_xw2<<<(N + 15) / 16, 256, 0, stream>>>(agg1, W2, b1, in_norm, out_norm, h2, N);
  gcn_pull32<<<(N + 7) / 8, 256, 0, stream>>>(rowptr, hist_d, col, h2, in_norm, b2, out, N);
}

// Round 3
// 407.192 us; speedup vs baseline: 5.6511x; 1.1130x over previous
//
#include <hip/hip_runtime.h>

// GCN 2-layer GraphConv (norm='both'), fp32.
// Round 3: rank-from-histogram (no cursor atomics in place), MLP-batched hist,
//          wide-gather pulls (1KB/instr, shuffle-reduce across edge slots).
//
// ws layout:
//   int   hist_s[N], hist_d[N], rowptr[N], bsum[1024], col[E]
//   float out_norm[N], in_norm[N], h1[64N] (alias h2[32N]),
//         agg1[64N] (alias int rank[E] — rank dead before pull64 writes agg1)

#define SCAN_BLK 1024  // elements per scan block (256 thr x 4)

// hist with rank capture: atomicAdd's return value IS the edge's rank within
// its dst bucket. 4 edges/thread for atomic MLP (8 outstanding per thread).
__global__ __launch_bounds__(256) void gcn_hist(const int* __restrict__ src,
                                                const int* __restrict__ dst,
                                                int* __restrict__ hist_s,
                                                int* __restrict__ hist_d,
                                                int* __restrict__ rank, int E) {
  int base = (blockIdx.x * 256 + threadIdx.x) * 4;
  if (base + 4 <= E) {
    int4 s4 = *(const int4*)(src + base);
    int4 d4 = *(const int4*)(dst + base);
    atomicAdd(&hist_s[s4.x], 1);
    atomicAdd(&hist_s[s4.y], 1);
    atomicAdd(&hist_s[s4.z], 1);
    atomicAdd(&hist_s[s4.w], 1);
    int4 r4;
    r4.x = atomicAdd(&hist_d[d4.x], 1);
    r4.y = atomicAdd(&hist_d[d4.y], 1);
    r4.z = atomicAdd(&hist_d[d4.z], 1);
    r4.w = atomicAdd(&hist_d[d4.w], 1);
    *(int4*)(rank + base) = r4;
  } else {
    for (int e = base; e < E; e++) {
      atomicAdd(&hist_s[src[e]], 1);
      rank[e] = atomicAdd(&hist_d[dst[e]], 1);
    }
  }
}

__global__ __launch_bounds__(256) void gcn_norm(const int* __restrict__ hist_s,
                                                const int* __restrict__ hist_d,
                                                float* __restrict__ out_norm,
                                                float* __restrict__ in_norm, int n) {
  int i = blockIdx.x * 256 + threadIdx.x;
  if (i < n) {
    out_norm[i] = rsqrtf(fmaxf((float)hist_s[i], 1.0f));
    in_norm[i]  = rsqrtf(fmaxf((float)hist_d[i], 1.0f));
  }
}

// ---- 3-kernel exclusive scan of hist_d -> rowptr ----
__global__ __launch_bounds__(256) void scan_local(const int* __restrict__ in,
                                                  int* __restrict__ out,
                                                  int* __restrict__ bsum, int n) {
  __shared__ int tmp[256];
  int t = threadIdx.x;
  int base = blockIdx.x * SCAN_BLK + t * 4;
  int v[4], s = 0;
#pragma unroll
  for (int i = 0; i < 4; i++) {
    v[i] = (base + i < n) ? in[base + i] : 0;
    s += v[i];
  }
  tmp[t] = s;
  __syncthreads();
#pragma unroll
  for (int off = 1; off < 256; off <<= 1) {
    int val = (t >= off) ? tmp[t - off] : 0;
    __syncthreads();
    tmp[t] += val;
    __syncthreads();
  }
  int run = tmp[t] - s;  // exclusive prefix
#pragma unroll
  for (int i = 0; i < 4; i++) {
    if (base + i < n) out[base + i] = run;
    run += v[i];
  }
  if (t == 255) bsum[blockIdx.x] = tmp[255];
}

__global__ __launch_bounds__(128) void scan_bsums(int* __restrict__ bsum, int nb) {
  __shared__ int tmp[128];
  int t = threadIdx.x;
  int v = (t < nb) ? bsum[t] : 0;
  tmp[t] = v;
  __syncthreads();
#pragma unroll
  for (int off = 1; off < 128; off <<= 1) {
    int val = (t >= off) ? tmp[t - off] : 0;
    __syncthreads();
    tmp[t] += val;
    __syncthreads();
  }
  if (t < nb) bsum[t] = tmp[t] - v;  // exclusive
}

__global__ __launch_bounds__(256) void scan_add(int* __restrict__ out,
                                                const int* __restrict__ bsum, int n) {
  int i = blockIdx.x * 256 + threadIdx.x;
  if (i < n) out[i] += bsum[i / SCAN_BLK];
}

// ---- CSR placement, atomic-free: col[rowptr[dst]+rank] = src ----
__global__ __launch_bounds__(256) void gcn_place(const int* __restrict__ src,
                                                 const int* __restrict__ dst,
                                                 const int* __restrict__ rowptr,
                                                 const int* __restrict__ rank,
                                                 int* __restrict__ col, int E) {
  int base = (blockIdx.x * 256 + threadIdx.x) * 4;
  if (base + 4 <= E) {
    int4 s4 = *(const int4*)(src + base);
    int4 d4 = *(const int4*)(dst + base);
    int4 r4 = *(const int4*)(rank + base);
    col[rowptr[d4.x] + r4.x] = s4.x;
    col[rowptr[d4.y] + r4.y] = s4.y;
    col[rowptr[d4.z] + r4.z] = s4.z;
    col[rowptr[d4.w] + r4.w] = s4.w;
  } else {
    for (int e = base; e < E; e++) col[rowptr[dst[e]] + rank[e]] = src[e];
  }
}

// ---- h1[N,64] = (x * out_norm[:,None]) @ W1[64,64] ----
__global__ __launch_bounds__(256) void gcn_xw1(const float* __restrict__ x,
                                               const float* __restrict__ W,
                                               const float* __restrict__ out_norm,
                                               float* __restrict__ h1, int n) {
  __shared__ float Ws[64 * 64];
  __shared__ float xs[16 * 64];
  int t = threadIdx.x;
#pragma unroll
  for (int i = 0; i < 16; i++) Ws[i * 256 + t] = W[i * 256 + t];
  int row0 = blockIdx.x * 16;
#pragma unroll
  for (int i = 0; i < 4; i++) {
    int idx = i * 256 + t;
    int r = idx >> 6, k = idx & 63;
    int row = row0 + r;
    xs[idx] = (row < n) ? x[row * 64 + k] * out_norm[row] : 0.0f;
  }
  __syncthreads();
  int c = t & 63, rq = t >> 6;
  float acc[4] = {0.f, 0.f, 0.f, 0.f};
#pragma unroll 16
  for (int k = 0; k < 64; k++) {
    float w = Ws[k * 64 + c];
#pragma unroll
    for (int rr = 0; rr < 4; rr++) acc[rr] += xs[(rq + rr * 4) * 64 + k] * w;
  }
#pragma unroll
  for (int rr = 0; rr < 4; rr++) {
    int row = row0 + rq + rr * 4;
    if (row < n) h1[row * 64 + c] = acc[rr];
  }
}

// ---- pull 64 feats: 1 wave/node; lane = (edge-slot 0..3, feat-quad 0..15)
//      one global instr gathers 4 edges x float4 = 1KB; shuffle-reduce slots.
__global__ __launch_bounds__(256) void gcn_pull64(const int* __restrict__ rowptr,
                                                  const int* __restrict__ deg,
                                                  const int* __restrict__ col,
                                                  const float* __restrict__ h,
                                                  float* __restrict__ agg, int n) {
  int t = threadIdx.x;
  int node = blockIdx.x * 4 + (t >> 6);
  if (node >= n) return;
  int l = t & 63;
  int sub = l >> 4;   // edge slot 0..3
  int fq  = l & 15;   // feature quad
  int beg = rowptr[node];
  int end = beg + deg[node];
  float4 a0 = {0, 0, 0, 0}, a1 = {0, 0, 0, 0};
  int j = beg;
  for (; j + 8 <= end; j += 8) {
    int s0 = col[j + sub];
    int s1 = col[j + 4 + sub];
    float4 v0 = ((const float4*)h)[(size_t)s0 * 16 + fq];
    float4 v1 = ((const float4*)h)[(size_t)s1 * 16 + fq];
    a0.x += v0.x; a0.y += v0.y; a0.z += v0.z; a0.w += v0.w;
    a1.x += v1.x; a1.y += v1.y; a1.z += v1.z; a1.w += v1.w;
  }
  for (; j < end; j += 4) {
    int jj = j + sub;
    if (jj < end) {
      int s = col[jj];
      float4 v = ((const float4*)h)[(size_t)s * 16 + fq];
      a0.x += v.x; a0.y += v.y; a0.z += v.z; a0.w += v.w;
    }
  }
  float4 acc;
  acc.x = a0.x + a1.x; acc.y = a0.y + a1.y; acc.z = a0.z + a1.z; acc.w = a0.w + a1.w;
#pragma unroll
  for (int d = 16; d <= 32; d <<= 1) {
    acc.x += __shfl_xor(acc.x, d);
    acc.y += __shfl_xor(acc.y, d);
    acc.z += __shfl_xor(acc.z, d);
    acc.w += __shfl_xor(acc.w, d);
  }
  if (sub == 0) ((float4*)agg)[(size_t)node * 16 + fq] = acc;
}

// ---- h2[N,32] = (relu(agg1 * in_norm + b1) * out_norm) @ W2[64,32] ----
__global__ __launch_bounds__(256) void gcn_xw2(const float* __restrict__ agg1,
                                               const float* __restrict__ W,
                                               const float* __restrict__ b1,
                                               const float* __restrict__ in_norm,
                                               const float* __restrict__ out_norm,
                                               float* __restrict__ h2, int n) {
  __shared__ float Ws[64 * 32];
  __shared__ float xs[16 * 64];
  int t = threadIdx.x;
#pragma unroll
  for (int i = 0; i < 8; i++) Ws[i * 256 + t] = W[i * 256 + t];
  int row0 = blockIdx.x * 16;
#pragma unroll
  for (int i = 0; i < 4; i++) {
    int idx = i * 256 + t;
    int r = idx >> 6, k = idx & 63;
    int row = row0 + r;
    float v = 0.0f;
    if (row < n)
      v = fmaxf(agg1[(size_t)row * 64 + k] * in_norm[row] + b1[k], 0.0f) * out_norm[row];
    xs[idx] = v;
  }
  __syncthreads();
  int c = t & 31, rq = t >> 5;
  float acc0 = 0.f, acc1 = 0.f;
#pragma unroll 16
  for (int k = 0; k < 64; k++) {
    float w = Ws[k * 32 + c];
    acc0 += xs[rq * 64 + k] * w;
    acc1 += xs[(rq + 8) * 64 + k] * w;
  }
  int row = row0 + rq;
  if (row < n) h2[(size_t)row * 32 + c] = acc0;
  row = row0 + rq + 8;
  if (row < n) h2[(size_t)row * 32 + c] = acc1;
}

// ---- pull 32 feats + fused epilogue: lane = (edge-slot 0..7, feat-quad 0..7)
__global__ __launch_bounds__(256) void gcn_pull32(const int* __restrict__ rowptr,
                                                  const int* __restrict__ deg,
                                                  const int* __restrict__ col,
                                                  const float* __restrict__ h,
                                                  const float* __restrict__ in_norm,
                                                  const float* __restrict__ b2,
                                                  float* __restrict__ out, int n) {
  int t = threadIdx.x;
  int node = blockIdx.x * 4 + (t >> 6);
  if (node >= n) return;
  int l = t & 63;
  int sub = l >> 3;   // edge slot 0..7
  int fq  = l & 7;    // feature quad 0..7
  int beg = rowptr[node];
  int end = beg + deg[node];
  float4 a0 = {0, 0, 0, 0}, a1 = {0, 0, 0, 0};
  int j = beg;
  for (; j + 16 <= end; j += 16) {
    int s0 = col[j + sub];
    int s1 = col[j + 8 + sub];
    float4 v0 = ((const float4*)h)[(size_t)s0 * 8 + fq];
    float4 v1 = ((const float4*)h)[(size_t)s1 * 8 + fq];
    a0.x += v0.x; a0.y += v0.y; a0.z += v0.z; a0.w += v0.w;
    a1.x += v1.x; a1.y += v1.y; a1.z += v1.z; a1.w += v1.w;
  }
  for (; j < end; j += 8) {
    int jj = j + sub;
    if (jj < end) {
      int s = col[jj];
      float4 v = ((const float4*)h)[(size_t)s * 8 + fq];
      a0.x += v.x; a0.y += v.y; a0.z += v.z; a0.w += v.w;
    }
  }
  float4 acc;
  acc.x = a0.x + a1.x; acc.y = a0.y + a1.y; acc.z = a0.z + a1.z; acc.w = a0.w + a1.w;
#pragma unroll
  for (int d = 8; d <= 32; d <<= 1) {
    acc.x += __shfl_xor(acc.x, d);
    acc.y += __shfl_xor(acc.y, d);
    acc.z += __shfl_xor(acc.z, d);
    acc.w += __shfl_xor(acc.w, d);
  }
  if (sub == 0) {
    float s = in_norm[node];
    float4 bb = ((const float4*)b2)[fq];
    acc.x = acc.x * s + bb.x;
    acc.y = acc.y * s + bb.y;
    acc.z = acc.z * s + bb.z;
    acc.w = acc.w * s + bb.w;
    ((float4*)out)[(size_t)node * 8 + fq] = acc;
  }
}

extern "C" void kernel_launch(void* const* d_in, const int* in_sizes, int n_in,
                              void* d_out, int out_size, void* d_ws, size_t ws_size,
                              hipStream_t stream) {
  const float* x   = (const float*)d_in[0];
  const int*   src = (const int*)d_in[1];
  const int*   dst = (const int*)d_in[2];
  const float* W1  = (const float*)d_in[3];
  const float* b1  = (const float*)d_in[4];
  const float* W2  = (const float*)d_in[5];
  const float* b2  = (const float*)d_in[6];
  float* out = (float*)d_out;

  const int N = in_sizes[0] / 64;   // 100000
  const int E = in_sizes[1];        // 1600000
  const int NB = (N + SCAN_BLK - 1) / SCAN_BLK;

  int* hist_s = (int*)d_ws;            // N
  int* hist_d = hist_s + N;            // N
  int* rowptr = hist_d + N;            // N
  int* bsum   = rowptr + N;            // 1024
  int* col    = bsum + 1024;           // E
  float* out_norm = (float*)(col + E); // N
  float* in_norm  = out_norm + N;      // N
  float* h1       = in_norm + N;       // 64N  (alias h2: 32N)
  float* agg1     = h1 + (size_t)64 * N; // 64N (alias rank[E] while building CSR)
  int*   rank     = (int*)agg1;        // E ints <= 64N floats; dead before pull64
  float* h2       = h1;                // h1 dead after pull64

  hipMemsetAsync(hist_s, 0, (size_t)2 * N * sizeof(int), stream);

  int gE4 = (E / 4 + 255) / 256 + 1;  // 4 edges/thread (+1 block covers tail)
  gcn_hist<<<gE4, 256, 0, stream>>>(src, dst, hist_s, hist_d, rank, E);
  gcn_norm<<<(N + 255) / 256, 256, 0, stream>>>(hist_s, hist_d, out_norm, in_norm, N);
  scan_local<<<NB, 256, 0, stream>>>(hist_d, rowptr, bsum, N);
  scan_bsums<<<1, 128, 0, stream>>>(bsum, NB);
  scan_add<<<(N + 255) / 256, 256, 0, stream>>>(rowptr, bsum, N);
  gcn_place<<<gE4, 256, 0, stream>>>(src, dst, rowptr, rank, col, E);
  gcn_xw1<<<(N + 15) / 16, 256, 0, stream>>>(x, W1, out_norm, h1, N);
  gcn_pull64<<<(N + 3) / 4, 256, 0, stream>>>(rowptr, hist_d, col, h1, agg1, N);
  gcn_xw2<<<(N + 15) / 16, 256, 0, stream>>>(agg1, W2, b1, in_norm, out_norm, h2, N);
  gcn_pull32<<<(N + 3) / 4, 256, 0, stream>>>(rowptr, hist_d, col, h2, in_norm, b2, out, N);
}